// Round 17
// baseline (146.621 us; speedup 1.0000x reference)
//
#include <hip/hip_runtime.h>

#define Bn 4
#define Ln 4096
#define Cn 128
#define DIn 256
#define NCn 128
#define LCn 32
#define ROWS (Bn*Ln)

typedef short s8v __attribute__((ext_vector_type(8)));
typedef short s4v __attribute__((ext_vector_type(4)));
typedef unsigned short u8v __attribute__((ext_vector_type(8)));
typedef unsigned short u4v __attribute__((ext_vector_type(4)));
typedef float f4v __attribute__((ext_vector_type(4)));
typedef float f2v __attribute__((ext_vector_type(2)));

__device__ __forceinline__ float siluf(float x){ return x / (1.f + __expf(-x)); }
__device__ __forceinline__ unsigned short bfr(float f){
  uint u = __float_as_uint(f);
  return (unsigned short)((u + 0x7fffu + ((u>>16)&1u)) >> 16);
}
__device__ __forceinline__ float bf2f(unsigned short u){ return __uint_as_float(((uint)u)<<16); }

// dt = softplus(r); w = exp(-dt) = sigmoid(-r). 3 trans ops total.
__device__ __forceinline__ void sp_w(float r, float& dtv, float& w){
  float e = __expf(-fabsf(r));
  float rc = 1.f / (1.f + e);
  dtv = fmaxf(r, 0.f) + __logf(1.f + e);
  w = (r > 0.f) ? e * rc : rc;
}

// LDS tile layout (Nx32 bf16 tile): subtiles [16r][32k]; granule (8 shorts)
// XOR-swizzled by ((r>>1)&3) -> wave s8v reads are ~2-way bank-aliased (free, m136).
__device__ __forceinline__ int tile_off(int r, int gran, int ghalf){
  return ((r>>4)<<9) + ((r&15)<<5) + (((gran ^ ((r>>1)&3)))<<3) + ghalf;
}

#define SMEMB 18432

// ---------------- G1 (bf16 MFMA): xz = (dir? rev xs : xs) @ W_in ----------------
__global__ __launch_bounds__(256) void k_g1(const float* __restrict__ x,
    const float* __restrict__ Wf, const float* __restrict__ Wb,
    unsigned short* __restrict__ xpf, unsigned short* __restrict__ xpb,
    unsigned short* __restrict__ zbf, unsigned short* __restrict__ zbb)
{
  const int dir = blockIdx.z;
  const float* __restrict__ W = dir ? Wb : Wf;
  unsigned short* __restrict__ xp = dir ? xpb : xpf;
  unsigned short* __restrict__ zb = dir ? zbb : zbf;
  const int row0 = blockIdx.x * 128;
  const int n0 = blockIdx.y;
  const int b = row0 >> 12;
  const int t0 = row0 & (Ln-1);
  const float* __restrict__ xb = x + (size_t)b * Cn * Ln;

  __shared__ __align__(16) char smem[SMEMB];
  short* Ast = (short*)smem;
  short* Bst = (short*)smem + 8*512;
  float* Te  = (float*)smem;

  const int tid = threadIdx.x;
  const int lane = tid & 63;
  const int wid = tid >> 6;
  const int wr = wid >> 1, wc = wid & 1;
  const int r16 = lane & 15, kg = lane >> 4;

  const int q = tid & 31, kq = tid >> 5;
  const int kbase = 4*kq;
  const int g_true = kq >> 1;
  const int ghalf = (kq & 1) * 4;

  f4v acc[4][4];
  #pragma unroll
  for (int i=0;i<4;++i)
    #pragma unroll
    for (int j=0;j<4;++j) acc[i][j] = (f4v){0.f,0.f,0.f,0.f};

  float4 va[4], vb[4];
  {
    #pragma unroll
    for (int kk=0;kk<4;++kk) {
      va[kk] = (dir==0)
        ? *(const float4*)(xb + (size_t)(kbase+kk)*Ln + t0 + 4*q)
        : *(const float4*)(xb + (size_t)(kbase+kk)*Ln + (Ln-4 - t0 - 4*q));
      vb[kk] = *(const float4*)(W + (size_t)(kbase+kk)*512 + n0*128 + 4*q);
    }
  }
  for (int ks=0; ks<4; ++ks) {
    if (ks) __syncthreads();
    #pragma unroll
    for (int e=0;e<4;++e) {
      int r = 4*q + e;
      int off = tile_off(r, g_true, ghalf);
      int c = dir ? (3-e) : e;
      s4v hv;
      #pragma unroll
      for (int kk=0;kk<4;++kk) hv[kk] = (short)bfr(((const float*)&va[kk])[c]);
      *(s4v*)&Ast[off] = hv;
    }
    #pragma unroll
    for (int e=0;e<4;++e) {
      int r = 4*q + e;
      int off = tile_off(r, g_true, ghalf);
      s4v hv;
      #pragma unroll
      for (int kk=0;kk<4;++kk) hv[kk] = (short)bfr(((const float*)&vb[kk])[e]);
      *(s4v*)&Bst[off] = hv;
    }
    __syncthreads();
    if (ks < 3) {
      const int k0n = (ks+1)*32;
      #pragma unroll
      for (int kk=0;kk<4;++kk) {
        va[kk] = (dir==0)
          ? *(const float4*)(xb + (size_t)(k0n+kbase+kk)*Ln + t0 + 4*q)
          : *(const float4*)(xb + (size_t)(k0n+kbase+kk)*Ln + (Ln-4 - t0 - 4*q));
        vb[kk] = *(const float4*)(W + (size_t)(k0n+kbase+kk)*512 + n0*128 + 4*q);
      }
    }
    const int gsh = ((kg ^ ((r16>>1)&3)) << 3);
    s8v fa[4], fb[4];
    #pragma unroll
    for (int m=0;m<4;++m) fa[m] = *(const s8v*)&Ast[(wr*4+m)*512 + r16*32 + gsh];
    #pragma unroll
    for (int n=0;n<4;++n) fb[n] = *(const s8v*)&Bst[(wc*4+n)*512 + r16*32 + gsh];
    #pragma unroll
    for (int m=0;m<4;++m)
      #pragma unroll
      for (int n=0;n<4;++n)
        acc[m][n] = __builtin_amdgcn_mfma_f32_16x16x32_bf16(fa[m], fb[n], acc[m][n], 0,0,0);
  }
  __syncthreads();
  float* Tw = Te + wid*1088;
  #pragma unroll
  for (int m=0;m<4;++m) {
    #pragma unroll
    for (int n=0;n<4;++n)
      #pragma unroll
      for (int v=0;v<4;++v)
        Tw[(kg*4+v)*68 + n*16 + r16] = acc[m][n][v];
    #pragma unroll
    for (int rr=0;rr<4;++rr) {
      int r = rr*4 + (lane>>4);
      int c4 = lane & 15;
      float4 v4 = *(const float4*)&Tw[r*68 + c4*4];
      int row = row0 + wr*64 + m*16 + r;
      int colL = wc*64 + c4*4;
      u4v u; u[0]=bfr(v4.x); u[1]=bfr(v4.y); u[2]=bfr(v4.z); u[3]=bfr(v4.w);
      if (n0 < 2) {
        *(u4v*)(xp + (size_t)row*256 + n0*128 + colL) = u;
      } else {
        *(u4v*)(zb + (size_t)row*256 + (n0-2)*128 + colL) = u;
      }
    }
  }
}

// ---------------- conv: xc = silu(conv(xp)) -> bf16 ----------------
__global__ __launch_bounds__(256) void k_conv(
    const unsigned short* __restrict__ xpf, const unsigned short* __restrict__ xpb,
    const float* __restrict__ cwf, const float* __restrict__ cwb,
    const float* __restrict__ cbf, const float* __restrict__ cbb,
    unsigned short* __restrict__ xcf, unsigned short* __restrict__ xcb)
{
  const int dir = blockIdx.y;
  const unsigned short* __restrict__ xpd = dir ? xpb : xpf;
  const float* __restrict__ cw = dir ? cwb : cwf;
  const float* __restrict__ cb = dir ? cbb : cbf;
  unsigned short* __restrict__ xc = dir ? xcb : xcf;
  const int n4 = ROWS * 64;
  for (int idx4 = blockIdx.x*256 + threadIdx.x; idx4 < n4; idx4 += gridDim.x*256) {
    int row = idx4 >> 6;
    int d0 = (idx4 & 63) * 4;
    u4v curu = *(const u4v*)(xpd + (size_t)row*256 + d0);
    u4v prevu = (u4v){0,0,0,0};
    if (row & (Ln-1)) prevu = *(const u4v*)(xpd + (size_t)(row-1)*256 + d0);
    float4 cwA = *(const float4*)(cw + d0*2);
    float4 cwB = *(const float4*)(cw + d0*2 + 4);
    float4 cb4 = *(const float4*)(cb + d0);
    u4v r;
    r[0] = bfr(siluf(fmaf(bf2f(prevu[0]),cwA.x, fmaf(bf2f(curu[0]),cwA.y, cb4.x))));
    r[1] = bfr(siluf(fmaf(bf2f(prevu[1]),cwA.z, fmaf(bf2f(curu[1]),cwA.w, cb4.y))));
    r[2] = bfr(siluf(fmaf(bf2f(prevu[2]),cwB.x, fmaf(bf2f(curu[2]),cwB.y, cb4.z))));
    r[3] = bfr(siluf(fmaf(bf2f(prevu[3]),cwB.z, fmaf(bf2f(curu[3]),cwB.w, cb4.w))));
    *(u4v*)(xc + (size_t)row*256 + d0) = r;
  }
}

// ---------------- G2 (bf16 MFMA): xdb = xc @ W_x ----------------
__global__ __launch_bounds__(256) void k_g2(
    const unsigned short* __restrict__ xcf, const unsigned short* __restrict__ xcb,
    const float* __restrict__ Wxf, const float* __restrict__ Wxb,
    float* __restrict__ xdbf, float* __restrict__ xdbb)
{
  const int dir = blockIdx.z;
  const unsigned short* __restrict__ xc = dir ? xcb : xcf;
  const float* __restrict__ Wx = dir ? Wxb : Wxf;
  float* __restrict__ xdb = dir ? xdbb : xdbf;
  const int row0 = blockIdx.x * 64;

  __shared__ __align__(16) short Ast[4*512];
  __shared__ __align__(16) short Bst[4*512];

  const int tid = threadIdx.x;
  const int lane = tid & 63;
  const int wid = tid >> 6;
  const int wr = wid >> 1, wc = wid & 1;
  const int r16 = lane & 15, kg = lane >> 4;
  const int ar = tid >> 2, ag = tid & 3;
  const int bn = tid & 63, bg = tid >> 6;

  f4v acc[2][2];
  #pragma unroll
  for (int i=0;i<2;++i)
    #pragma unroll
    for (int j=0;j<2;++j) acc[i][j] = (f4v){0.f,0.f,0.f,0.f};

  for (int ks=0; ks<8; ++ks) {
    const int k0 = ks*32;
    if (ks) __syncthreads();
    {
      u8v u = *(const u8v*)(xc + (size_t)(row0+ar)*256 + k0 + ag*8);
      *(u8v*)&Ast[tile_off(ar, ag, 0)] = u;
    }
    {
      s8v hv;
      #pragma unroll
      for (int i=0;i<8;++i) {
        int k = k0 + bg*8 + i;
        float f = (bn < 40) ? Wx[(size_t)k*40 + bn] : 0.f;
        hv[i] = (short)bfr(f);
      }
      *(s8v*)&Bst[tile_off(bn, bg, 0)] = hv;
    }
    __syncthreads();
    const int gsh = ((kg ^ ((r16>>1)&3)) << 3);
    s8v fa[2], fb[2];
    #pragma unroll
    for (int m=0;m<2;++m) fa[m] = *(const s8v*)&Ast[(wr*2+m)*512 + r16*32 + gsh];
    #pragma unroll
    for (int n=0;n<2;++n) fb[n] = *(const s8v*)&Bst[(wc*2+n)*512 + r16*32 + gsh];
    #pragma unroll
    for (int m=0;m<2;++m)
      #pragma unroll
      for (int n=0;n<2;++n)
        acc[m][n] = __builtin_amdgcn_mfma_f32_16x16x32_bf16(fa[m], fb[n], acc[m][n], 0,0,0);
  }
  #pragma unroll
  for (int m=0;m<2;++m)
    #pragma unroll
    for (int n=0;n<2;++n) {
      int col = wc*32 + n*16 + r16;
      if (col < 40) {
        #pragma unroll
        for (int v=0;v<4;++v) {
          int row = row0 + wr*32 + m*16 + kg*4 + v;
          xdb[(size_t)row*40 + col] = acc[m][n][v];
        }
      }
    }
}

// ---------------- pass1: per-chunk local scan; wave-uniform scalar S reads; hk bf16 -------
__global__ __launch_bounds__(128,4) void k_pass1(
    const float* __restrict__ xdbf, const float* __restrict__ xdbb,
    const unsigned short* __restrict__ xcf, const unsigned short* __restrict__ xcb,
    const float* __restrict__ Wdtf, const float* __restrict__ Wdtb,
    const float* __restrict__ bdtf, const float* __restrict__ bdtb,
    const float* __restrict__ Alf, const float* __restrict__ Alb,
    float* __restrict__ sdtf, float* __restrict__ sdtb,
    unsigned short* __restrict__ hkf, unsigned short* __restrict__ hkb)
{
  const int dir = blockIdx.y;
  const float* __restrict__ xdb = dir ? xdbb : xdbf;
  const unsigned short* __restrict__ xc = dir ? xcb : xcf;
  const float* __restrict__ Wdt = dir ? Wdtb : Wdtf;
  const float* __restrict__ bdt = dir ? bdtb : bdtf;
  const float* __restrict__ Al  = dir ? Alb  : Alf;
  float* __restrict__ sdt = dir ? sdtb : sdtf;
  unsigned short* __restrict__ hk = dir ? hkb : hkf;
  const int dh = blockIdx.x & 1;
  const int cc = blockIdx.x >> 1;
  const int b = cc >> 7, c = cc & 127;
  const int t0 = c * LCn;
  const int tid = threadIdx.x;
  const int d = dh*128 + tid;
  float Areg[16];
  bool st = true;
  #pragma unroll
  for (int s=0;s<16;++s) {
    Areg[s] = -__expf(Al[d*16+s]);
    st = st && (fabsf(Areg[s] + (float)(s+1)) <= 3e-5f*(float)(s+1));
  }
  f2v wdt2[4];
  #pragma unroll
  for (int j=0;j<4;++j) wdt2[j] = (f2v){Wdt[(2*j)*256+d], Wdt[(2*j+1)*256+d]};
  const float bd = bdt[d];
  f2v h2[8];
  #pragma unroll
  for (int i=0;i<8;++i) h2[i] = (f2v){0.f,0.f};
  float sacc = 0.f;
  const unsigned short* xcp = xc + (size_t)(b*Ln + t0)*256 + d;
  const float* __restrict__ Sg = xdb + (size_t)(b*Ln + t0)*40;   // block-uniform base
  if (st) {
    for (int t=0;t<LCn;++t) {
      const float* __restrict__ Sp = Sg + (size_t)t*40;          // wave-uniform row
      float4 sA = *(const float4*)&Sp[0];
      float4 sB = *(const float4*)&Sp[4];
      f2v r2 = (f2v){sA.x,sA.y}*wdt2[0] + (f2v){sA.z,sA.w}*wdt2[1];
      r2 = (f2v){sB.x,sB.y}*wdt2[2] + r2;
      r2 = (f2v){sB.z,sB.w}*wdt2[3] + r2;
      float rr = bd + r2.x + r2.y;
      float dtv, wv;
      sp_w(rr, dtv, wv);
      float4 b0 = *(const float4*)&Sp[8];
      float4 b1 = *(const float4*)&Sp[12];
      float4 b2 = *(const float4*)&Sp[16];
      float4 b3 = *(const float4*)&Sp[20];
      float xv = bf2f(xcp[(size_t)t*256]);
      float u = dtv * xv;
      sacc += dtv;
      float w2s = wv*wv;
      float w4 = w2s*w2s, w8 = w4*w4;
      f2v wstep = (f2v){w2s, w2s};
      f2v wpa = (f2v){wv, w2s};
      f2v wpb = wpa * (f2v){w8, w8};
      f2v u2 = (f2v){u, u};
      h2[0] = h2[0]*wpa + u2*(f2v){b0.x,b0.y}; wpa *= wstep;
      h2[4] = h2[4]*wpb + u2*(f2v){b2.x,b2.y}; wpb *= wstep;
      h2[1] = h2[1]*wpa + u2*(f2v){b0.z,b0.w}; wpa *= wstep;
      h2[5] = h2[5]*wpb + u2*(f2v){b2.z,b2.w}; wpb *= wstep;
      h2[2] = h2[2]*wpa + u2*(f2v){b1.x,b1.y}; wpa *= wstep;
      h2[6] = h2[6]*wpb + u2*(f2v){b3.x,b3.y}; wpb *= wstep;
      h2[3] = h2[3]*wpa + u2*(f2v){b1.z,b1.w};
      h2[7] = h2[7]*wpb + u2*(f2v){b3.z,b3.w};
    }
  } else {
    for (int t=0;t<LCn;++t) {
      const float* __restrict__ Sp = Sg + (size_t)t*40;
      float4 sA = *(const float4*)&Sp[0];
      float4 sB = *(const float4*)&Sp[4];
      float rr = bd;
      rr = fmaf(sA.x,wdt2[0].x, fmaf(sA.y,wdt2[0].y, fmaf(sA.z,wdt2[1].x, fmaf(sA.w,wdt2[1].y, rr))));
      rr = fmaf(sB.x,wdt2[2].x, fmaf(sB.y,wdt2[2].y, fmaf(sB.z,wdt2[3].x, fmaf(sB.w,wdt2[3].y, rr))));
      float dtv, wv;
      sp_w(rr, dtv, wv);
      float bq[16];
      #pragma unroll
      for (int i=0;i<4;++i) *(float4*)&bq[4*i] = *(const float4*)&Sp[8 + 4*i];
      float xv = bf2f(xcp[(size_t)t*256]);
      float u = dtv * xv;
      sacc += dtv;
      #pragma unroll
      for (int s=0;s<16;++s) {
        float hv = (s&1) ? h2[s>>1].y : h2[s>>1].x;
        hv = fmaf(hv, __expf(dtv*Areg[s]), u*bq[s]);
        if (s&1) h2[s>>1].y = hv; else h2[s>>1].x = hv;
      }
    }
  }
  sdt[(size_t)(b*NCn + c)*256 + d] = sacc;
  #pragma unroll
  for (int i=0;i<8;++i) {
    hk[(size_t)((b*NCn + c)*16 + 2*i)*256 + d]   = bfr(h2[i].x);
    hk[(size_t)((b*NCn + c)*16 + 2*i+1)*256 + d] = bfr(h2[i].y);
  }
}

// ---------------- pass2: inter-chunk recurrence (bf16 hk, f32 carry), prefetch ----------
__global__ __launch_bounds__(256) void k_pass2(
    const float* __restrict__ Alf, const float* __restrict__ Alb,
    const float* __restrict__ sdtf, const float* __restrict__ sdtb,
    unsigned short* __restrict__ hkf, unsigned short* __restrict__ hkb)
{
  const int dir = blockIdx.y;
  const float* __restrict__ Al  = dir ? Alb : Alf;
  const float* __restrict__ sdt = dir ? sdtb : sdtf;
  unsigned short* __restrict__ hk = dir ? hkb : hkf;
  int g = blockIdx.x*256 + threadIdx.x;
  int d = g & 255, s = (g >> 8) & 15, b = g >> 12;
  float Ad = -__expf(Al[d*16+s]);
  float h = 0.f;
  float sd_n = sdt[(size_t)(b*NCn)*256 + d];
  size_t hi_n = (size_t)((b*NCn)*16 + s)*256 + d;
  float he_n = bf2f(hk[hi_n]);
  for (int c=0;c<NCn;++c) {
    float sd = sd_n, he = he_n;
    size_t hi = hi_n;
    if (c+1 < NCn) {
      int bc = b*NCn + c + 1;
      sd_n = sdt[(size_t)bc*256 + d];
      hi_n = (size_t)(bc*16 + s)*256 + d;
      he_n = bf2f(hk[hi_n]);
    }
    hk[hi] = bfr(h);
    h = fmaf(__expf(Ad*sd), h, he);
  }
}

// ---------------- pass3: replay; wave-uniform scalar S reads; gate silu(z) -> yg bf16 ------
__global__ __launch_bounds__(128,4) void k_pass3(
    const float* __restrict__ xdbf, const float* __restrict__ xdbb,
    const unsigned short* __restrict__ xcf, const unsigned short* __restrict__ xcb,
    const float* __restrict__ Wdtf, const float* __restrict__ Wdtb,
    const float* __restrict__ bdtf, const float* __restrict__ bdtb,
    const float* __restrict__ Alf, const float* __restrict__ Alb,
    const float* __restrict__ Dvf, const float* __restrict__ Dvb,
    const unsigned short* __restrict__ hkf, const unsigned short* __restrict__ hkb,
    const unsigned short* __restrict__ zbf, const unsigned short* __restrict__ zbb,
    unsigned short* __restrict__ ygf, unsigned short* __restrict__ ygb)
{
  const int dir = blockIdx.y;
  const float* __restrict__ xdb = dir ? xdbb : xdbf;
  const unsigned short* __restrict__ xc = dir ? xcb : xcf;
  const float* __restrict__ Wdt = dir ? Wdtb : Wdtf;
  const float* __restrict__ bdt = dir ? bdtb : bdtf;
  const float* __restrict__ Al  = dir ? Alb  : Alf;
  const float* __restrict__ Dv  = dir ? Dvb  : Dvf;
  const unsigned short* __restrict__ hk = dir ? hkb : hkf;
  const unsigned short* __restrict__ zbd = dir ? zbb : zbf;
  unsigned short* __restrict__ yg = dir ? ygb : ygf;
  const int dh = blockIdx.x & 1;
  const int cc = blockIdx.x >> 1;
  const int b = cc >> 7, c = cc & 127;
  const int t0 = c * LCn;
  const int tid = threadIdx.x;
  const int d = dh*128 + tid;
  float Areg[16];
  bool st = true;
  #pragma unroll
  for (int s=0;s<16;++s) {
    Areg[s] = -__expf(Al[d*16+s]);
    st = st && (fabsf(Areg[s] + (float)(s+1)) <= 3e-5f*(float)(s+1));
  }
  f2v wdt2[4];
  #pragma unroll
  for (int j=0;j<4;++j) wdt2[j] = (f2v){Wdt[(2*j)*256+d], Wdt[(2*j+1)*256+d]};
  const float bd = bdt[d];
  const float Dd = Dv[d];
  f2v h2[8];
  #pragma unroll
  for (int i=0;i<8;++i)
    h2[i] = (f2v){bf2f(hk[(size_t)((b*NCn + c)*16 + 2*i)*256 + d]),
                  bf2f(hk[(size_t)((b*NCn + c)*16 + 2*i+1)*256 + d])};
  const unsigned short* xcp = xc + (size_t)(b*Ln + t0)*256 + d;
  const unsigned short* zbp = zbd + (size_t)(b*Ln + t0)*256 + d;
  unsigned short* ygp = yg + (size_t)(b*Ln + t0)*256 + d;
  const float* __restrict__ Sg = xdb + (size_t)(b*Ln + t0)*40;   // block-uniform base
  if (st) {
    for (int t=0;t<LCn;++t) {
      const float* __restrict__ Sp = Sg + (size_t)t*40;
      float4 sA = *(const float4*)&Sp[0];
      float4 sB = *(const float4*)&Sp[4];
      f2v r2 = (f2v){sA.x,sA.y}*wdt2[0] + (f2v){sA.z,sA.w}*wdt2[1];
      r2 = (f2v){sB.x,sB.y}*wdt2[2] + r2;
      r2 = (f2v){sB.z,sB.w}*wdt2[3] + r2;
      float rr = bd + r2.x + r2.y;
      float dtv, wv;
      sp_w(rr, dtv, wv);
      float4 b0 = *(const float4*)&Sp[8];
      float4 b1 = *(const float4*)&Sp[12];
      float4 b2 = *(const float4*)&Sp[16];
      float4 b3 = *(const float4*)&Sp[20];
      float4 c0 = *(const float4*)&Sp[24];
      float4 c1 = *(const float4*)&Sp[28];
      float4 c2 = *(const float4*)&Sp[32];
      float4 c3 = *(const float4*)&Sp[36];
      float xv = bf2f(xcp[(size_t)t*256]);
      float u = dtv * xv;
      float w2s = wv*wv;
      float w4 = w2s*w2s, w8 = w4*w4;
      f2v wstep = (f2v){w2s, w2s};
      f2v wpa = (f2v){wv, w2s};
      f2v wpb = wpa * (f2v){w8, w8};
      f2v u2 = (f2v){u, u};
      f2v yA = (f2v){0.f,0.f}, yB = (f2v){0.f,0.f};
      h2[0] = h2[0]*wpa + u2*(f2v){b0.x,b0.y}; yA = h2[0]*(f2v){c0.x,c0.y} + yA; wpa *= wstep;
      h2[4] = h2[4]*wpb + u2*(f2v){b2.x,b2.y}; yB = h2[4]*(f2v){c2.x,c2.y} + yB; wpb *= wstep;
      h2[1] = h2[1]*wpa + u2*(f2v){b0.z,b0.w}; yA = h2[1]*(f2v){c0.z,c0.w} + yA; wpa *= wstep;
      h2[5] = h2[5]*wpb + u2*(f2v){b2.z,b2.w}; yB = h2[5]*(f2v){c2.z,c2.w} + yB; wpb *= wstep;
      h2[2] = h2[2]*wpa + u2*(f2v){b1.x,b1.y}; yA = h2[2]*(f2v){c1.x,c1.y} + yA; wpa *= wstep;
      h2[6] = h2[6]*wpb + u2*(f2v){b3.x,b3.y}; yB = h2[6]*(f2v){c3.x,c3.y} + yB; wpb *= wstep;
      h2[3] = h2[3]*wpa + u2*(f2v){b1.z,b1.w}; yA = h2[3]*(f2v){c1.z,c1.w} + yA;
      h2[7] = h2[7]*wpb + u2*(f2v){b3.z,b3.w}; yB = h2[7]*(f2v){c3.z,c3.w} + yB;
      float y = yA.x + yA.y + yB.x + yB.y;
      y = fmaf(Dd, xv, y);
      float zv = bf2f(zbp[(size_t)t*256]);
      ygp[(size_t)t*256] = bfr(y * siluf(zv));
    }
  } else {
    for (int t=0;t<LCn;++t) {
      const float* __restrict__ Sp = Sg + (size_t)t*40;
      float4 sA = *(const float4*)&Sp[0];
      float4 sB = *(const float4*)&Sp[4];
      float rr = bd;
      rr = fmaf(sA.x,wdt2[0].x, fmaf(sA.y,wdt2[0].y, fmaf(sA.z,wdt2[1].x, fmaf(sA.w,wdt2[1].y, rr))));
      rr = fmaf(sB.x,wdt2[2].x, fmaf(sB.y,wdt2[2].y, fmaf(sB.z,wdt2[3].x, fmaf(sB.w,wdt2[3].y, rr))));
      float dtv, wv;
      sp_w(rr, dtv, wv);
      float bq[16], cq[16];
      #pragma unroll
      for (int i=0;i<4;++i) {
        *(float4*)&bq[4*i] = *(const float4*)&Sp[8 + 4*i];
        *(float4*)&cq[4*i] = *(const float4*)&Sp[24 + 4*i];
      }
      float xv = bf2f(xcp[(size_t)t*256]);
      float u = dtv * xv;
      float y = 0.f;
      #pragma unroll
      for (int s=0;s<16;++s) {
        float hv = (s&1) ? h2[s>>1].y : h2[s>>1].x;
        hv = fmaf(hv, __expf(dtv*Areg[s]), u*bq[s]);
        if (s&1) h2[s>>1].y = hv; else h2[s>>1].x = hv;
        y = fmaf(hv, cq[s], y);
      }
      y = fmaf(Dd, xv, y);
      float zv = bf2f(zbp[(size_t)t*256]);
      ygp[(size_t)t*256] = bfr(y * siluf(zv));
    }
  }
}

// ---------------- Gout (bf16 MFMA): ypart[khalf] = sum_dir yg[dir] @ W_out[dir][khalf] ------
__global__ __launch_bounds__(256) void k_gout(
    const unsigned short* __restrict__ ygf, const unsigned short* __restrict__ ygb,
    const float* __restrict__ Wof, const float* __restrict__ Wob,
    float* __restrict__ yp)
{
  const int row0 = blockIdx.x * 64;
  const int khalf = blockIdx.y;
  float* __restrict__ ypart = yp + (size_t)khalf * ROWS * 128;
  const int b = row0 >> 12;
  const int l0 = row0 & (Ln-1);

  __shared__ __align__(16) char smem[SMEMB];
  short* Ast = (short*)smem;
  short* Bst = (short*)smem + 4*512;
  float* Te  = (float*)smem;

  const int tid = threadIdx.x;
  const int lane = tid & 63;
  const int wid = tid >> 6;
  const int wr = wid >> 1, wc = wid & 1;
  const int r16 = lane & 15, kg = lane >> 4;

  const int ar = tid >> 2, ag = tid & 3;
  const int q = tid & 31, kq = tid >> 5;
  const int kbase = 4*kq;
  const int g_true = kq >> 1;
  const int ghalf = (kq & 1) * 4;

  f4v acc[2][4];
  #pragma unroll
  for (int i=0;i<2;++i)
    #pragma unroll
    for (int j=0;j<4;++j) acc[i][j] = (f4v){0.f,0.f,0.f,0.f};

  for (int ks=0; ks<8; ++ks) {
    const int dir = ks >> 2;
    const int kk0 = khalf*128 + (ks & 3)*32;
    const unsigned short* __restrict__ ygd = dir ? ygb : ygf;
    const float* __restrict__ Wod = dir ? Wob : Wof;
    if (ks) __syncthreads();
    {
      int rl = l0 + ar;
      size_t srow = (size_t)b*Ln + (dir ? (Ln-1-rl) : rl);
      u8v u = *(const u8v*)(ygd + srow*256 + kk0 + ag*8);
      *(u8v*)&Ast[tile_off(ar, ag, 0)] = u;
    }
    {
      float4 vb[4];
      #pragma unroll
      for (int kk=0;kk<4;++kk)
        vb[kk] = *(const float4*)(Wod + (size_t)(kk0+kbase+kk)*128 + 4*q);
      #pragma unroll
      for (int e=0;e<4;++e) {
        int r = 4*q + e;
        int off = tile_off(r, g_true, ghalf);
        s4v hv;
        #pragma unroll
        for (int kk=0;kk<4;++kk) hv[kk] = (short)bfr(((const float*)&vb[kk])[e]);
        *(s4v*)&Bst[off] = hv;
      }
    }
    __syncthreads();
    const int gsh = ((kg ^ ((r16>>1)&3)) << 3);
    s8v fa[2], fb[4];
    #pragma unroll
    for (int m=0;m<2;++m) fa[m] = *(const s8v*)&Ast[(wr*2+m)*512 + r16*32 + gsh];
    #pragma unroll
    for (int n=0;n<4;++n) fb[n] = *(const s8v*)&Bst[(wc*4+n)*512 + r16*32 + gsh];
    #pragma unroll
    for (int m=0;m<2;++m)
      #pragma unroll
      for (int n=0;n<4;++n)
        acc[m][n] = __builtin_amdgcn_mfma_f32_16x16x32_bf16(fa[m], fb[n], acc[m][n], 0,0,0);
  }
  __syncthreads();
  float* Tw = Te + wid*1088;
  #pragma unroll
  for (int m=0;m<2;++m) {
    #pragma unroll
    for (int n=0;n<4;++n)
      #pragma unroll
      for (int v=0;v<4;++v)
        Tw[(kg*4+v)*68 + n*16 + r16] = acc[m][n][v];
    #pragma unroll
    for (int rr=0;rr<4;++rr) {
      int r = rr*4 + (lane>>4);
      int c4 = lane & 15;
      float4 v4 = *(const float4*)&Tw[r*68 + c4*4];
      int row = row0 + wr*32 + m*16 + r;
      *(float4*)(ypart + (size_t)row*128 + wc*64 + c4*4) = v4;
    }
    __syncthreads();
  }
}

// ---------------- GroupNorm stats + partial-sum (2 partials) -> ysum ----------------
__global__ __launch_bounds__(256) void k_gnstat(const float* __restrict__ yp,
    float* __restrict__ ysum, float* __restrict__ part)
{
  const int bg = blockIdx.x >> 4;
  const int blk = blockIdx.x & 15;
  const int b = bg >> 2, g = bg & 3;
  const size_t P = (size_t)ROWS*128;
  float s=0.f, q=0.f;
  #pragma unroll
  for (int i=0;i<8;++i) {
    int e4 = blk*2048 + threadIdx.x + i*256;
    int l = e4 >> 3, c4 = e4 & 7;
    size_t base = (size_t)(b*Ln + l)*128 + g*32 + c4*4;
    float4 v0 = *(const float4*)(yp + base);
    float4 v1 = *(const float4*)(yp + P + base);
    float4 v;
    v.x = v0.x+v1.x;
    v.y = v0.y+v1.y;
    v.z = v0.z+v1.z;
    v.w = v0.w+v1.w;
    *(float4*)(ysum + base) = v;
    s += v.x+v.y+v.z+v.w;
    q = fmaf(v.x,v.x, fmaf(v.y,v.y, fmaf(v.z,v.z, fmaf(v.w,v.w, q))));
  }
  __shared__ float rs[256], rq[256];
  rs[threadIdx.x]=s; rq[threadIdx.x]=q;
  __syncthreads();
  for (int off=128; off>0; off>>=1) {
    if (threadIdx.x < off) { rs[threadIdx.x]+=rs[threadIdx.x+off]; rq[threadIdx.x]+=rq[threadIdx.x+off]; }
    __syncthreads();
  }
  if (threadIdx.x==0) { part[blockIdx.x*2]=rs[0]; part[blockIdx.x*2+1]=rq[0]; }
}

__global__ void k_gnred(const float* __restrict__ part, float* __restrict__ mr)
{
  int t = threadIdx.x;
  if (t < 16) {
    float s=0.f,q=0.f;
    for (int k=0;k<16;++k){ s+=part[(t*16+k)*2]; q+=part[(t*16+k)*2+1]; }
    const float inv = 1.f/131072.f;
    float mean = s*inv;
    float var = fmaf(-mean, mean, q*inv);
    mr[t*2] = mean;
    mr[t*2+1] = rsqrtf(var + 1e-5f);
  }
}

// ---------------- GN apply + silu + residual ----------------
__global__ __launch_bounds__(256) void k_gnapply(const float* __restrict__ ysum,
    const float* __restrict__ mr, const float* __restrict__ gamma, const float* __restrict__ beta,
    const float* __restrict__ x, float* __restrict__ out)
{
  const int b = blockIdx.x >> 6;
  const int l0 = (blockIdx.x & 63) * 64;
  __shared__ float T[64][132];
  const int tid = threadIdx.x;
  #pragma unroll
  for (int j=0;j<8;++j) {
    int f = tid + j*256;
    int l = f >> 5, c4 = f & 31;
    *(float4*)&T[l][c4*4] = *(const float4*)(ysum + (size_t)(b*Ln + l0 + l)*128 + c4*4);
  }
  __syncthreads();
  #pragma unroll
  for (int j=0;j<8;++j) {
    int f = tid + j*256;
    int c = f >> 4, lv = f & 15;
    int bg = b*4 + (c>>5);
    float mean = mr[bg*2];
    float rstd = mr[bg*2+1];
    float gam = gamma[c], bet = beta[c];
    size_t base = (size_t)(b*Cn + c)*Ln + l0 + lv*4;
    float4 xv = *(const float4*)(x + base);
    float4 r;
    r.x = siluf(fmaf((T[lv*4+0][c]-mean)*rstd, gam, bet)) + xv.x;
    r.y = siluf(fmaf((T[lv*4+1][c]-mean)*rstd, gam, bet)) + xv.y;
    r.z = siluf(fmaf((T[lv*4+2][c]-mean)*rstd, gam, bet)) + xv.z;
    r.w = siluf(fmaf((T[lv*4+3][c]-mean)*rstd, gam, bet)) + xv.w;
    *(float4*)(out + base) = r;
  }
}

extern "C" void kernel_launch(void* const* d_in, const int* in_sizes, int n_in,
                              void* d_out, int out_size, void* d_ws, size_t ws_size,
                              hipStream_t stream) {
  const float* x      = (const float*)d_in[0];
  const float* W_in_f = (const float*)d_in[1];
  const float* cw_f   = (const float*)d_in[2];
  const float* cb_f   = (const float*)d_in[3];
  const float* Wx_f   = (const float*)d_in[4];
  const float* Wdt_f  = (const float*)d_in[5];
  const float* bdt_f  = (const float*)d_in[6];
  const float* Al_f   = (const float*)d_in[7];
  const float* D_f    = (const float*)d_in[8];
  const float* Wo_f   = (const float*)d_in[9];
  const float* W_in_b = (const float*)d_in[10];
  const float* cw_b   = (const float*)d_in[11];
  const float* cb_b   = (const float*)d_in[12];
  const float* Wx_b   = (const float*)d_in[13];
  const float* Wdt_b  = (const float*)d_in[14];
  const float* bdt_b  = (const float*)d_in[15];
  const float* Al_b   = (const float*)d_in[16];
  const float* D_b    = (const float*)d_in[17];
  const float* Wo_b   = (const float*)d_in[18];
  const float* gamma  = (const float*)d_in[19];
  const float* beta   = (const float*)d_in[20];
  float* out = (float*)d_out;

  float* w = (float*)d_ws;
  size_t o = 0;
  float* xpr0 = w + o; o += (size_t)ROWS*256;  // xp bf16 region; yp aliases after conv
  float* xpr1 = w + o; o += (size_t)ROWS*256;
  unsigned short* xc0 = (unsigned short*)(w + o); o += (size_t)ROWS*128;
  unsigned short* xc1 = (unsigned short*)(w + o); o += (size_t)ROWS*128;
  unsigned short* zb0 = (unsigned short*)(w + o); o += (size_t)ROWS*128;
  unsigned short* zb1 = (unsigned short*)(w + o); o += (size_t)ROWS*128;
  unsigned short* yg0 = (unsigned short*)(w + o); o += (size_t)ROWS*128;
  unsigned short* yg1 = (unsigned short*)(w + o); o += (size_t)ROWS*128;
  float* xdb0 = w + o; o += (size_t)ROWS*40;   // dead after pass3 -> ysum alias
  float* xdb1 = w + o; o += (size_t)ROWS*40;
  float* sdt0 = w + o; o += (size_t)Bn*NCn*256;
  float* sdt1 = w + o; o += (size_t)Bn*NCn*256;
  unsigned short* hk0 = (unsigned short*)(w + o); o += (size_t)Bn*NCn*16*128;  // bf16
  unsigned short* hk1 = (unsigned short*)(w + o); o += (size_t)Bn*NCn*16*128;
  float* part = w + o; o += 2048;
  float* mr   = w + o; o += 32;
  unsigned short* xp0 = (unsigned short*)xpr0;
  unsigned short* xp1 = (unsigned short*)xpr1;
  float* yp   = xpr0;   // 2 x ROWS*128 f32 = xpr0 (xp dead after conv)
  float* ysum = xdb0;
  if (ws_size < o*sizeof(float)) return;

  k_g1<<<dim3(ROWS/128, 4, 2), 256, 0, stream>>>(x, W_in_f, W_in_b, xp0, xp1, zb0, zb1);
  k_conv<<<dim3(1024, 2), 256, 0, stream>>>(xp0, xp1, cw_f, cw_b, cb_f, cb_b, xc0, xc1);
  k_g2<<<dim3(ROWS/64, 1, 2), 256, 0, stream>>>(xc0, xc1, Wx_f, Wx_b, xdb0, xdb1);
  k_pass1<<<dim3(Bn*NCn*2, 2), 128, 0, stream>>>(xdb0, xdb1, xc0, xc1, Wdt_f, Wdt_b,
                                                 bdt_f, bdt_b, Al_f, Al_b, sdt0, sdt1, hk0, hk1);
  k_pass2<<<dim3(64, 2), 256, 0, stream>>>(Al_f, Al_b, sdt0, sdt1, hk0, hk1);
  k_pass3<<<dim3(Bn*NCn*2, 2), 128, 0, stream>>>(xdb0, xdb1, xc0, xc1, Wdt_f, Wdt_b,
                                                 bdt_f, bdt_b, Al_f, Al_b, D_f, D_b,
                                                 hk0, hk1, zb0, zb1, yg0, yg1);
  k_gout<<<dim3(ROWS/64, 2), 256, 0, stream>>>(yg0, yg1, Wo_f, Wo_b, yp);
  k_gnstat<<<dim3(256), 256, 0, stream>>>(yp, ysum, part);
  k_gnred<<<dim3(1), 64, 0, stream>>>(part, mr);
  k_gnapply<<<dim3(256), 256, 0, stream>>>(ysum, mr, gamma, beta, x, out);
}

// Round 18
// 142.366 us; speedup vs baseline: 1.0299x; 1.0299x over previous
//
#include <hip/hip_runtime.h>

#define Bn 4
#define Ln 4096
#define Cn 128
#define DIn 256
#define NCn 128
#define LCn 32
#define ROWS (Bn*Ln)

typedef short s8v __attribute__((ext_vector_type(8)));
typedef short s4v __attribute__((ext_vector_type(4)));
typedef unsigned short u8v __attribute__((ext_vector_type(8)));
typedef unsigned short u4v __attribute__((ext_vector_type(4)));
typedef float f4v __attribute__((ext_vector_type(4)));
typedef float f2v __attribute__((ext_vector_type(2)));

__device__ __forceinline__ float siluf(float x){ return x / (1.f + __expf(-x)); }
__device__ __forceinline__ unsigned short bfr(float f){
  uint u = __float_as_uint(f);
  return (unsigned short)((u + 0x7fffu + ((u>>16)&1u)) >> 16);
}
__device__ __forceinline__ float bf2f(unsigned short u){ return __uint_as_float(((uint)u)<<16); }

// dt = softplus(r); w = exp(-dt) = sigmoid(-r). 3 trans ops total.
__device__ __forceinline__ void sp_w(float r, float& dtv, float& w){
  float e = __expf(-fabsf(r));
  float rc = 1.f / (1.f + e);
  dtv = fmaxf(r, 0.f) + __logf(1.f + e);
  w = (r > 0.f) ? e * rc : rc;
}

// LDS tile layout (Nx32 bf16 tile): subtiles [16r][32k]; granule (8 shorts)
// XOR-swizzled by ((r>>1)&3) -> wave s8v reads are ~2-way bank-aliased (free, m136).
__device__ __forceinline__ int tile_off(int r, int gran, int ghalf){
  return ((r>>4)<<9) + ((r&15)<<5) + (((gran ^ ((r>>1)&3)))<<3) + ghalf;
}

#define SMEMB 18432

// ---------------- G1 (bf16 MFMA): xz = (dir? rev xs : xs) @ W_in ----------------
__global__ __launch_bounds__(256) void k_g1(const float* __restrict__ x,
    const float* __restrict__ Wf, const float* __restrict__ Wb,
    unsigned short* __restrict__ xpf, unsigned short* __restrict__ xpb,
    unsigned short* __restrict__ zbf, unsigned short* __restrict__ zbb)
{
  const int dir = blockIdx.z;
  const float* __restrict__ W = dir ? Wb : Wf;
  unsigned short* __restrict__ xp = dir ? xpb : xpf;
  unsigned short* __restrict__ zb = dir ? zbb : zbf;
  const int row0 = blockIdx.x * 128;
  const int n0 = blockIdx.y;
  const int b = row0 >> 12;
  const int t0 = row0 & (Ln-1);
  const float* __restrict__ xb = x + (size_t)b * Cn * Ln;

  __shared__ __align__(16) char smem[SMEMB];
  short* Ast = (short*)smem;
  short* Bst = (short*)smem + 8*512;
  float* Te  = (float*)smem;

  const int tid = threadIdx.x;
  const int lane = tid & 63;
  const int wid = tid >> 6;
  const int wr = wid >> 1, wc = wid & 1;
  const int r16 = lane & 15, kg = lane >> 4;

  const int q = tid & 31, kq = tid >> 5;
  const int kbase = 4*kq;
  const int g_true = kq >> 1;
  const int ghalf = (kq & 1) * 4;

  f4v acc[4][4];
  #pragma unroll
  for (int i=0;i<4;++i)
    #pragma unroll
    for (int j=0;j<4;++j) acc[i][j] = (f4v){0.f,0.f,0.f,0.f};

  float4 va[4], vb[4];
  {
    #pragma unroll
    for (int kk=0;kk<4;++kk) {
      va[kk] = (dir==0)
        ? *(const float4*)(xb + (size_t)(kbase+kk)*Ln + t0 + 4*q)
        : *(const float4*)(xb + (size_t)(kbase+kk)*Ln + (Ln-4 - t0 - 4*q));
      vb[kk] = *(const float4*)(W + (size_t)(kbase+kk)*512 + n0*128 + 4*q);
    }
  }
  for (int ks=0; ks<4; ++ks) {
    if (ks) __syncthreads();
    #pragma unroll
    for (int e=0;e<4;++e) {
      int r = 4*q + e;
      int off = tile_off(r, g_true, ghalf);
      int c = dir ? (3-e) : e;
      s4v hv;
      #pragma unroll
      for (int kk=0;kk<4;++kk) hv[kk] = (short)bfr(((const float*)&va[kk])[c]);
      *(s4v*)&Ast[off] = hv;
    }
    #pragma unroll
    for (int e=0;e<4;++e) {
      int r = 4*q + e;
      int off = tile_off(r, g_true, ghalf);
      s4v hv;
      #pragma unroll
      for (int kk=0;kk<4;++kk) hv[kk] = (short)bfr(((const float*)&vb[kk])[e]);
      *(s4v*)&Bst[off] = hv;
    }
    __syncthreads();
    if (ks < 3) {
      const int k0n = (ks+1)*32;
      #pragma unroll
      for (int kk=0;kk<4;++kk) {
        va[kk] = (dir==0)
          ? *(const float4*)(xb + (size_t)(k0n+kbase+kk)*Ln + t0 + 4*q)
          : *(const float4*)(xb + (size_t)(k0n+kbase+kk)*Ln + (Ln-4 - t0 - 4*q));
        vb[kk] = *(const float4*)(W + (size_t)(k0n+kbase+kk)*512 + n0*128 + 4*q);
      }
    }
    const int gsh = ((kg ^ ((r16>>1)&3)) << 3);
    s8v fa[4], fb[4];
    #pragma unroll
    for (int m=0;m<4;++m) fa[m] = *(const s8v*)&Ast[(wr*4+m)*512 + r16*32 + gsh];
    #pragma unroll
    for (int n=0;n<4;++n) fb[n] = *(const s8v*)&Bst[(wc*4+n)*512 + r16*32 + gsh];
    #pragma unroll
    for (int m=0;m<4;++m)
      #pragma unroll
      for (int n=0;n<4;++n)
        acc[m][n] = __builtin_amdgcn_mfma_f32_16x16x32_bf16(fa[m], fb[n], acc[m][n], 0,0,0);
  }
  __syncthreads();
  float* Tw = Te + wid*1088;
  #pragma unroll
  for (int m=0;m<4;++m) {
    #pragma unroll
    for (int n=0;n<4;++n)
      #pragma unroll
      for (int v=0;v<4;++v)
        Tw[(kg*4+v)*68 + n*16 + r16] = acc[m][n][v];
    #pragma unroll
    for (int rr=0;rr<4;++rr) {
      int r = rr*4 + (lane>>4);
      int c4 = lane & 15;
      float4 v4 = *(const float4*)&Tw[r*68 + c4*4];
      int row = row0 + wr*64 + m*16 + r;
      int colL = wc*64 + c4*4;
      u4v u; u[0]=bfr(v4.x); u[1]=bfr(v4.y); u[2]=bfr(v4.z); u[3]=bfr(v4.w);
      if (n0 < 2) {
        *(u4v*)(xp + (size_t)row*256 + n0*128 + colL) = u;
      } else {
        *(u4v*)(zb + (size_t)row*256 + (n0-2)*128 + colL) = u;
      }
    }
  }
}

// ---------------- conv: xc = silu(conv(xp)) -> bf16 ----------------
__global__ __launch_bounds__(256) void k_conv(
    const unsigned short* __restrict__ xpf, const unsigned short* __restrict__ xpb,
    const float* __restrict__ cwf, const float* __restrict__ cwb,
    const float* __restrict__ cbf, const float* __restrict__ cbb,
    unsigned short* __restrict__ xcf, unsigned short* __restrict__ xcb)
{
  const int dir = blockIdx.y;
  const unsigned short* __restrict__ xpd = dir ? xpb : xpf;
  const float* __restrict__ cw = dir ? cwb : cwf;
  const float* __restrict__ cb = dir ? cbb : cbf;
  unsigned short* __restrict__ xc = dir ? xcb : xcf;
  const int n4 = ROWS * 64;
  for (int idx4 = blockIdx.x*256 + threadIdx.x; idx4 < n4; idx4 += gridDim.x*256) {
    int row = idx4 >> 6;
    int d0 = (idx4 & 63) * 4;
    u4v curu = *(const u4v*)(xpd + (size_t)row*256 + d0);
    u4v prevu = (u4v){0,0,0,0};
    if (row & (Ln-1)) prevu = *(const u4v*)(xpd + (size_t)(row-1)*256 + d0);
    float4 cwA = *(const float4*)(cw + d0*2);
    float4 cwB = *(const float4*)(cw + d0*2 + 4);
    float4 cb4 = *(const float4*)(cb + d0);
    u4v r;
    r[0] = bfr(siluf(fmaf(bf2f(prevu[0]),cwA.x, fmaf(bf2f(curu[0]),cwA.y, cb4.x))));
    r[1] = bfr(siluf(fmaf(bf2f(prevu[1]),cwA.z, fmaf(bf2f(curu[1]),cwA.w, cb4.y))));
    r[2] = bfr(siluf(fmaf(bf2f(prevu[2]),cwB.x, fmaf(bf2f(curu[2]),cwB.y, cb4.z))));
    r[3] = bfr(siluf(fmaf(bf2f(prevu[3]),cwB.z, fmaf(bf2f(curu[3]),cwB.w, cb4.w))));
    *(u4v*)(xc + (size_t)row*256 + d0) = r;
  }
}

// ---------------- G2 (bf16 MFMA): xdb = xc @ W_x ----------------
__global__ __launch_bounds__(256) void k_g2(
    const unsigned short* __restrict__ xcf, const unsigned short* __restrict__ xcb,
    const float* __restrict__ Wxf, const float* __restrict__ Wxb,
    float* __restrict__ xdbf, float* __restrict__ xdbb)
{
  const int dir = blockIdx.z;
  const unsigned short* __restrict__ xc = dir ? xcb : xcf;
  const float* __restrict__ Wx = dir ? Wxb : Wxf;
  float* __restrict__ xdb = dir ? xdbb : xdbf;
  const int row0 = blockIdx.x * 64;

  __shared__ __align__(16) short Ast[4*512];
  __shared__ __align__(16) short Bst[4*512];

  const int tid = threadIdx.x;
  const int lane = tid & 63;
  const int wid = tid >> 6;
  const int wr = wid >> 1, wc = wid & 1;
  const int r16 = lane & 15, kg = lane >> 4;
  const int ar = tid >> 2, ag = tid & 3;
  const int bn = tid & 63, bg = tid >> 6;

  f4v acc[2][2];
  #pragma unroll
  for (int i=0;i<2;++i)
    #pragma unroll
    for (int j=0;j<2;++j) acc[i][j] = (f4v){0.f,0.f,0.f,0.f};

  for (int ks=0; ks<8; ++ks) {
    const int k0 = ks*32;
    if (ks) __syncthreads();
    {
      u8v u = *(const u8v*)(xc + (size_t)(row0+ar)*256 + k0 + ag*8);
      *(u8v*)&Ast[tile_off(ar, ag, 0)] = u;
    }
    {
      s8v hv;
      #pragma unroll
      for (int i=0;i<8;++i) {
        int k = k0 + bg*8 + i;
        float f = (bn < 40) ? Wx[(size_t)k*40 + bn] : 0.f;
        hv[i] = (short)bfr(f);
      }
      *(s8v*)&Bst[tile_off(bn, bg, 0)] = hv;
    }
    __syncthreads();
    const int gsh = ((kg ^ ((r16>>1)&3)) << 3);
    s8v fa[2], fb[2];
    #pragma unroll
    for (int m=0;m<2;++m) fa[m] = *(const s8v*)&Ast[(wr*2+m)*512 + r16*32 + gsh];
    #pragma unroll
    for (int n=0;n<2;++n) fb[n] = *(const s8v*)&Bst[(wc*2+n)*512 + r16*32 + gsh];
    #pragma unroll
    for (int m=0;m<2;++m)
      #pragma unroll
      for (int n=0;n<2;++n)
        acc[m][n] = __builtin_amdgcn_mfma_f32_16x16x32_bf16(fa[m], fb[n], acc[m][n], 0,0,0);
  }
  #pragma unroll
  for (int m=0;m<2;++m)
    #pragma unroll
    for (int n=0;n<2;++n) {
      int col = wc*32 + n*16 + r16;
      if (col < 40) {
        #pragma unroll
        for (int v=0;v<4;++v) {
          int row = row0 + wr*32 + m*16 + kg*4 + v;
          xdb[(size_t)row*40 + col] = acc[m][n][v];
        }
      }
    }
}

// ---------------- pass1: per-chunk local scan; hk stored bf16 ----------------
__global__ __launch_bounds__(128,4) void k_pass1(
    const float* __restrict__ xdbf, const float* __restrict__ xdbb,
    const unsigned short* __restrict__ xcf, const unsigned short* __restrict__ xcb,
    const float* __restrict__ Wdtf, const float* __restrict__ Wdtb,
    const float* __restrict__ bdtf, const float* __restrict__ bdtb,
    const float* __restrict__ Alf, const float* __restrict__ Alb,
    float* __restrict__ sdtf, float* __restrict__ sdtb,
    unsigned short* __restrict__ hkf, unsigned short* __restrict__ hkb)
{
  const int dir = blockIdx.y;
  const float* __restrict__ xdb = dir ? xdbb : xdbf;
  const unsigned short* __restrict__ xc = dir ? xcb : xcf;
  const float* __restrict__ Wdt = dir ? Wdtb : Wdtf;
  const float* __restrict__ bdt = dir ? bdtb : bdtf;
  const float* __restrict__ Al  = dir ? Alb  : Alf;
  float* __restrict__ sdt = dir ? sdtb : sdtf;
  unsigned short* __restrict__ hk = dir ? hkb : hkf;
  const int dh = blockIdx.x & 1;
  const int cc = blockIdx.x >> 1;
  const int b = cc >> 7, c = cc & 127;
  const int t0 = c * LCn;
  __shared__ float S[LCn*32];
  const int tid = threadIdx.x;
  #pragma unroll
  for (int j=0;j<6;++j) {
    int idx = tid + j*128;
    int t = idx/24, jj = idx - t*24;
    S[t*32 + jj] = xdb[(size_t)(b*Ln + t0 + t)*40 + jj];
  }
  const int d = dh*128 + tid;
  float Areg[16];
  bool st = true;
  #pragma unroll
  for (int s=0;s<16;++s) {
    Areg[s] = -__expf(Al[d*16+s]);
    st = st && (fabsf(Areg[s] + (float)(s+1)) <= 3e-5f*(float)(s+1));
  }
  f2v wdt2[4];
  #pragma unroll
  for (int j=0;j<4;++j) wdt2[j] = (f2v){Wdt[(2*j)*256+d], Wdt[(2*j+1)*256+d]};
  const float bd = bdt[d];
  f2v h2[8];
  #pragma unroll
  for (int i=0;i<8;++i) h2[i] = (f2v){0.f,0.f};
  float sacc = 0.f;
  const unsigned short* xcp = xc + (size_t)(b*Ln + t0)*256 + d;
  __syncthreads();
  if (st) {
    for (int t=0;t<LCn;++t) {
      float4 sA = *(const float4*)&S[t*32];
      float4 sB = *(const float4*)&S[t*32+4];
      f2v r2 = (f2v){sA.x,sA.y}*wdt2[0] + (f2v){sA.z,sA.w}*wdt2[1];
      r2 = (f2v){sB.x,sB.y}*wdt2[2] + r2;
      r2 = (f2v){sB.z,sB.w}*wdt2[3] + r2;
      float rr = bd + r2.x + r2.y;
      float dtv, wv;
      sp_w(rr, dtv, wv);
      float4 b0 = *(const float4*)&S[t*32+8];
      float4 b1 = *(const float4*)&S[t*32+12];
      float4 b2 = *(const float4*)&S[t*32+16];
      float4 b3 = *(const float4*)&S[t*32+20];
      float xv = bf2f(xcp[(size_t)t*256]);
      float u = dtv * xv;
      sacc += dtv;
      float w2s = wv*wv;
      float w4 = w2s*w2s, w8 = w4*w4;
      f2v wstep = (f2v){w2s, w2s};
      f2v wpa = (f2v){wv, w2s};
      f2v wpb = wpa * (f2v){w8, w8};
      f2v u2 = (f2v){u, u};
      h2[0] = h2[0]*wpa + u2*(f2v){b0.x,b0.y}; wpa *= wstep;
      h2[4] = h2[4]*wpb + u2*(f2v){b2.x,b2.y}; wpb *= wstep;
      h2[1] = h2[1]*wpa + u2*(f2v){b0.z,b0.w}; wpa *= wstep;
      h2[5] = h2[5]*wpb + u2*(f2v){b2.z,b2.w}; wpb *= wstep;
      h2[2] = h2[2]*wpa + u2*(f2v){b1.x,b1.y}; wpa *= wstep;
      h2[6] = h2[6]*wpb + u2*(f2v){b3.x,b3.y}; wpb *= wstep;
      h2[3] = h2[3]*wpa + u2*(f2v){b1.z,b1.w};
      h2[7] = h2[7]*wpb + u2*(f2v){b3.z,b3.w};
    }
  } else {
    for (int t=0;t<LCn;++t) {
      float4 sA = *(const float4*)&S[t*32];
      float4 sB = *(const float4*)&S[t*32+4];
      float rr = bd;
      rr = fmaf(sA.x,wdt2[0].x, fmaf(sA.y,wdt2[0].y, fmaf(sA.z,wdt2[1].x, fmaf(sA.w,wdt2[1].y, rr))));
      rr = fmaf(sB.x,wdt2[2].x, fmaf(sB.y,wdt2[2].y, fmaf(sB.z,wdt2[3].x, fmaf(sB.w,wdt2[3].y, rr))));
      float dtv, wv;
      sp_w(rr, dtv, wv);
      float bq[16];
      #pragma unroll
      for (int i=0;i<4;++i) *(float4*)&bq[4*i] = *(const float4*)&S[t*32 + 8 + 4*i];
      float xv = bf2f(xcp[(size_t)t*256]);
      float u = dtv * xv;
      sacc += dtv;
      #pragma unroll
      for (int s=0;s<16;++s) {
        float hv = (s&1) ? h2[s>>1].y : h2[s>>1].x;
        hv = fmaf(hv, __expf(dtv*Areg[s]), u*bq[s]);
        if (s&1) h2[s>>1].y = hv; else h2[s>>1].x = hv;
      }
    }
  }
  sdt[(size_t)(b*NCn + c)*256 + d] = sacc;
  #pragma unroll
  for (int i=0;i<8;++i) {
    hk[(size_t)((b*NCn + c)*16 + 2*i)*256 + d]   = bfr(h2[i].x);
    hk[(size_t)((b*NCn + c)*16 + 2*i+1)*256 + d] = bfr(h2[i].y);
  }
}

// ---------------- pass2: inter-chunk recurrence (bf16 hk, f32 carry), prefetch ----------
__global__ __launch_bounds__(256) void k_pass2(
    const float* __restrict__ Alf, const float* __restrict__ Alb,
    const float* __restrict__ sdtf, const float* __restrict__ sdtb,
    unsigned short* __restrict__ hkf, unsigned short* __restrict__ hkb)
{
  const int dir = blockIdx.y;
  const float* __restrict__ Al  = dir ? Alb : Alf;
  const float* __restrict__ sdt = dir ? sdtb : sdtf;
  unsigned short* __restrict__ hk = dir ? hkb : hkf;
  int g = blockIdx.x*256 + threadIdx.x;
  int d = g & 255, s = (g >> 8) & 15, b = g >> 12;
  float Ad = -__expf(Al[d*16+s]);
  float h = 0.f;
  float sd_n = sdt[(size_t)(b*NCn)*256 + d];
  size_t hi_n = (size_t)((b*NCn)*16 + s)*256 + d;
  float he_n = bf2f(hk[hi_n]);
  for (int c=0;c<NCn;++c) {
    float sd = sd_n, he = he_n;
    size_t hi = hi_n;
    if (c+1 < NCn) {
      int bc = b*NCn + c + 1;
      sd_n = sdt[(size_t)bc*256 + d];
      hi_n = (size_t)(bc*16 + s)*256 + d;
      he_n = bf2f(hk[hi_n]);
    }
    hk[hi] = bfr(h);
    h = fmaf(__expf(Ad*sd), h, he);
  }
}

// ---------------- pass3: replay; bf16 hk carry-in; gate silu(z) -> yg bf16 ----------
__global__ __launch_bounds__(128,4) void k_pass3(
    const float* __restrict__ xdbf, const float* __restrict__ xdbb,
    const unsigned short* __restrict__ xcf, const unsigned short* __restrict__ xcb,
    const float* __restrict__ Wdtf, const float* __restrict__ Wdtb,
    const float* __restrict__ bdtf, const float* __restrict__ bdtb,
    const float* __restrict__ Alf, const float* __restrict__ Alb,
    const float* __restrict__ Dvf, const float* __restrict__ Dvb,
    const unsigned short* __restrict__ hkf, const unsigned short* __restrict__ hkb,
    const unsigned short* __restrict__ zbf, const unsigned short* __restrict__ zbb,
    unsigned short* __restrict__ ygf, unsigned short* __restrict__ ygb)
{
  const int dir = blockIdx.y;
  const float* __restrict__ xdb = dir ? xdbb : xdbf;
  const unsigned short* __restrict__ xc = dir ? xcb : xcf;
  const float* __restrict__ Wdt = dir ? Wdtb : Wdtf;
  const float* __restrict__ bdt = dir ? bdtb : bdtf;
  const float* __restrict__ Al  = dir ? Alb  : Alf;
  const float* __restrict__ Dv  = dir ? Dvb  : Dvf;
  const unsigned short* __restrict__ hk = dir ? hkb : hkf;
  const unsigned short* __restrict__ zbd = dir ? zbb : zbf;
  unsigned short* __restrict__ yg = dir ? ygb : ygf;
  const int dh = blockIdx.x & 1;
  const int cc = blockIdx.x >> 1;
  const int b = cc >> 7, c = cc & 127;
  const int t0 = c * LCn;
  __shared__ float S[LCn*48];
  const int tid = threadIdx.x;
  #pragma unroll
  for (int j=0;j<10;++j) {
    int idx = tid + j*128;
    int t = idx/40, jj = idx - t*40;
    S[t*48 + jj] = xdb[(size_t)(b*Ln + t0 + t)*40 + jj];
  }
  const int d = dh*128 + tid;
  float Areg[16];
  bool st = true;
  #pragma unroll
  for (int s=0;s<16;++s) {
    Areg[s] = -__expf(Al[d*16+s]);
    st = st && (fabsf(Areg[s] + (float)(s+1)) <= 3e-5f*(float)(s+1));
  }
  f2v wdt2[4];
  #pragma unroll
  for (int j=0;j<4;++j) wdt2[j] = (f2v){Wdt[(2*j)*256+d], Wdt[(2*j+1)*256+d]};
  const float bd = bdt[d];
  const float Dd = Dv[d];
  f2v h2[8];
  #pragma unroll
  for (int i=0;i<8;++i)
    h2[i] = (f2v){bf2f(hk[(size_t)((b*NCn + c)*16 + 2*i)*256 + d]),
                  bf2f(hk[(size_t)((b*NCn + c)*16 + 2*i+1)*256 + d])};
  const unsigned short* xcp = xc + (size_t)(b*Ln + t0)*256 + d;
  const unsigned short* zbp = zbd + (size_t)(b*Ln + t0)*256 + d;
  unsigned short* ygp = yg + (size_t)(b*Ln + t0)*256 + d;
  __syncthreads();
  if (st) {
    for (int t=0;t<LCn;++t) {
      float4 sA = *(const float4*)&S[t*48];
      float4 sB = *(const float4*)&S[t*48+4];
      f2v r2 = (f2v){sA.x,sA.y}*wdt2[0] + (f2v){sA.z,sA.w}*wdt2[1];
      r2 = (f2v){sB.x,sB.y}*wdt2[2] + r2;
      r2 = (f2v){sB.z,sB.w}*wdt2[3] + r2;
      float rr = bd + r2.x + r2.y;
      float dtv, wv;
      sp_w(rr, dtv, wv);
      float4 b0 = *(const float4*)&S[t*48+8];
      float4 b1 = *(const float4*)&S[t*48+12];
      float4 b2 = *(const float4*)&S[t*48+16];
      float4 b3 = *(const float4*)&S[t*48+20];
      float4 c0 = *(const float4*)&S[t*48+24];
      float4 c1 = *(const float4*)&S[t*48+28];
      float4 c2 = *(const float4*)&S[t*48+32];
      float4 c3 = *(const float4*)&S[t*48+36];
      float xv = bf2f(xcp[(size_t)t*256]);
      float u = dtv * xv;
      float w2s = wv*wv;
      float w4 = w2s*w2s, w8 = w4*w4;
      f2v wstep = (f2v){w2s, w2s};
      f2v wpa = (f2v){wv, w2s};
      f2v wpb = wpa * (f2v){w8, w8};
      f2v u2 = (f2v){u, u};
      f2v yA = (f2v){0.f,0.f}, yB = (f2v){0.f,0.f};
      h2[0] = h2[0]*wpa + u2*(f2v){b0.x,b0.y}; yA = h2[0]*(f2v){c0.x,c0.y} + yA; wpa *= wstep;
      h2[4] = h2[4]*wpb + u2*(f2v){b2.x,b2.y}; yB = h2[4]*(f2v){c2.x,c2.y} + yB; wpb *= wstep;
      h2[1] = h2[1]*wpa + u2*(f2v){b0.z,b0.w}; yA = h2[1]*(f2v){c0.z,c0.w} + yA; wpa *= wstep;
      h2[5] = h2[5]*wpb + u2*(f2v){b2.z,b2.w}; yB = h2[5]*(f2v){c2.z,c2.w} + yB; wpb *= wstep;
      h2[2] = h2[2]*wpa + u2*(f2v){b1.x,b1.y}; yA = h2[2]*(f2v){c1.x,c1.y} + yA; wpa *= wstep;
      h2[6] = h2[6]*wpb + u2*(f2v){b3.x,b3.y}; yB = h2[6]*(f2v){c3.x,c3.y} + yB; wpb *= wstep;
      h2[3] = h2[3]*wpa + u2*(f2v){b1.z,b1.w}; yA = h2[3]*(f2v){c1.z,c1.w} + yA;
      h2[7] = h2[7]*wpb + u2*(f2v){b3.z,b3.w}; yB = h2[7]*(f2v){c3.z,c3.w} + yB;
      float y = yA.x + yA.y + yB.x + yB.y;
      y = fmaf(Dd, xv, y);
      float zv = bf2f(zbp[(size_t)t*256]);
      ygp[(size_t)t*256] = bfr(y * siluf(zv));
    }
  } else {
    for (int t=0;t<LCn;++t) {
      float4 sA = *(const float4*)&S[t*48];
      float4 sB = *(const float4*)&S[t*48+4];
      float rr = bd;
      rr = fmaf(sA.x,wdt2[0].x, fmaf(sA.y,wdt2[0].y, fmaf(sA.z,wdt2[1].x, fmaf(sA.w,wdt2[1].y, rr))));
      rr = fmaf(sB.x,wdt2[2].x, fmaf(sB.y,wdt2[2].y, fmaf(sB.z,wdt2[3].x, fmaf(sB.w,wdt2[3].y, rr))));
      float dtv, wv;
      sp_w(rr, dtv, wv);
      float bq[16], cq[16];
      #pragma unroll
      for (int i=0;i<4;++i) {
        *(float4*)&bq[4*i] = *(const float4*)&S[t*48 + 8 + 4*i];
        *(float4*)&cq[4*i] = *(const float4*)&S[t*48 + 24 + 4*i];
      }
      float xv = bf2f(xcp[(size_t)t*256]);
      float u = dtv * xv;
      float y = 0.f;
      #pragma unroll
      for (int s=0;s<16;++s) {
        float hv = (s&1) ? h2[s>>1].y : h2[s>>1].x;
        hv = fmaf(hv, __expf(dtv*Areg[s]), u*bq[s]);
        if (s&1) h2[s>>1].y = hv; else h2[s>>1].x = hv;
        y = fmaf(hv, cq[s], y);
      }
      y = fmaf(Dd, xv, y);
      float zv = bf2f(zbp[(size_t)t*256]);
      ygp[(size_t)t*256] = bfr(y * siluf(zv));
    }
  }
}

// ---------------- Gout (bf16 MFMA): ypart[khalf] = sum_dir yg[dir] @ W_out[dir][khalf] ------
__global__ __launch_bounds__(256) void k_gout(
    const unsigned short* __restrict__ ygf, const unsigned short* __restrict__ ygb,
    const float* __restrict__ Wof, const float* __restrict__ Wob,
    float* __restrict__ yp)
{
  const int row0 = blockIdx.x * 64;
  const int khalf = blockIdx.y;
  float* __restrict__ ypart = yp + (size_t)khalf * ROWS * 128;
  const int b = row0 >> 12;
  const int l0 = row0 & (Ln-1);

  __shared__ __align__(16) char smem[SMEMB];
  short* Ast = (short*)smem;
  short* Bst = (short*)smem + 4*512;
  float* Te  = (float*)smem;

  const int tid = threadIdx.x;
  const int lane = tid & 63;
  const int wid = tid >> 6;
  const int wr = wid >> 1, wc = wid & 1;
  const int r16 = lane & 15, kg = lane >> 4;

  const int ar = tid >> 2, ag = tid & 3;
  const int q = tid & 31, kq = tid >> 5;
  const int kbase = 4*kq;
  const int g_true = kq >> 1;
  const int ghalf = (kq & 1) * 4;

  f4v acc[2][4];
  #pragma unroll
  for (int i=0;i<2;++i)
    #pragma unroll
    for (int j=0;j<4;++j) acc[i][j] = (f4v){0.f,0.f,0.f,0.f};

  for (int ks=0; ks<8; ++ks) {
    const int dir = ks >> 2;
    const int kk0 = khalf*128 + (ks & 3)*32;
    const unsigned short* __restrict__ ygd = dir ? ygb : ygf;
    const float* __restrict__ Wod = dir ? Wob : Wof;
    if (ks) __syncthreads();
    {
      int rl = l0 + ar;
      size_t srow = (size_t)b*Ln + (dir ? (Ln-1-rl) : rl);
      u8v u = *(const u8v*)(ygd + srow*256 + kk0 + ag*8);
      *(u8v*)&Ast[tile_off(ar, ag, 0)] = u;
    }
    {
      float4 vb[4];
      #pragma unroll
      for (int kk=0;kk<4;++kk)
        vb[kk] = *(const float4*)(Wod + (size_t)(kk0+kbase+kk)*128 + 4*q);
      #pragma unroll
      for (int e=0;e<4;++e) {
        int r = 4*q + e;
        int off = tile_off(r, g_true, ghalf);
        s4v hv;
        #pragma unroll
        for (int kk=0;kk<4;++kk) hv[kk] = (short)bfr(((const float*)&vb[kk])[e]);
        *(s4v*)&Bst[off] = hv;
      }
    }
    __syncthreads();
    const int gsh = ((kg ^ ((r16>>1)&3)) << 3);
    s8v fa[2], fb[4];
    #pragma unroll
    for (int m=0;m<2;++m) fa[m] = *(const s8v*)&Ast[(wr*2+m)*512 + r16*32 + gsh];
    #pragma unroll
    for (int n=0;n<4;++n) fb[n] = *(const s8v*)&Bst[(wc*4+n)*512 + r16*32 + gsh];
    #pragma unroll
    for (int m=0;m<2;++m)
      #pragma unroll
      for (int n=0;n<4;++n)
        acc[m][n] = __builtin_amdgcn_mfma_f32_16x16x32_bf16(fa[m], fb[n], acc[m][n], 0,0,0);
  }
  __syncthreads();
  float* Tw = Te + wid*1088;
  #pragma unroll
  for (int m=0;m<2;++m) {
    #pragma unroll
    for (int n=0;n<4;++n)
      #pragma unroll
      for (int v=0;v<4;++v)
        Tw[(kg*4+v)*68 + n*16 + r16] = acc[m][n][v];
    #pragma unroll
    for (int rr=0;rr<4;++rr) {
      int r = rr*4 + (lane>>4);
      int c4 = lane & 15;
      float4 v4 = *(const float4*)&Tw[r*68 + c4*4];
      int row = row0 + wr*32 + m*16 + r;
      *(float4*)(ypart + (size_t)row*128 + wc*64 + c4*4) = v4;
    }
    __syncthreads();
  }
}

// ---------------- GroupNorm stats + partial-sum (2 partials) -> ysum ----------------
__global__ __launch_bounds__(256) void k_gnstat(const float* __restrict__ yp,
    float* __restrict__ ysum, float* __restrict__ part)
{
  const int bg = blockIdx.x >> 4;
  const int blk = blockIdx.x & 15;
  const int b = bg >> 2, g = bg & 3;
  const size_t P = (size_t)ROWS*128;
  float s=0.f, q=0.f;
  #pragma unroll
  for (int i=0;i<8;++i) {
    int e4 = blk*2048 + threadIdx.x + i*256;
    int l = e4 >> 3, c4 = e4 & 7;
    size_t base = (size_t)(b*Ln + l)*128 + g*32 + c4*4;
    float4 v0 = *(const float4*)(yp + base);
    float4 v1 = *(const float4*)(yp + P + base);
    float4 v;
    v.x = v0.x+v1.x;
    v.y = v0.y+v1.y;
    v.z = v0.z+v1.z;
    v.w = v0.w+v1.w;
    *(float4*)(ysum + base) = v;
    s += v.x+v.y+v.z+v.w;
    q = fmaf(v.x,v.x, fmaf(v.y,v.y, fmaf(v.z,v.z, fmaf(v.w,v.w, q))));
  }
  __shared__ float rs[256], rq[256];
  rs[threadIdx.x]=s; rq[threadIdx.x]=q;
  __syncthreads();
  for (int off=128; off>0; off>>=1) {
    if (threadIdx.x < off) { rs[threadIdx.x]+=rs[threadIdx.x+off]; rq[threadIdx.x]+=rq[threadIdx.x+off]; }
    __syncthreads();
  }
  if (threadIdx.x==0) { part[blockIdx.x*2]=rs[0]; part[blockIdx.x*2+1]=rq[0]; }
}

__global__ void k_gnred(const float* __restrict__ part, float* __restrict__ mr)
{
  int t = threadIdx.x;
  if (t < 16) {
    float s=0.f,q=0.f;
    for (int k=0;k<16;++k){ s+=part[(t*16+k)*2]; q+=part[(t*16+k)*2+1]; }
    const float inv = 1.f/131072.f;
    float mean = s*inv;
    float var = fmaf(-mean, mean, q*inv);
    mr[t*2] = mean;
    mr[t*2+1] = rsqrtf(var + 1e-5f);
  }
}

// ---------------- GN apply + silu + residual ----------------
__global__ __launch_bounds__(256) void k_gnapply(const float* __restrict__ ysum,
    const float* __restrict__ mr, const float* __restrict__ gamma, const float* __restrict__ beta,
    const float* __restrict__ x, float* __restrict__ out)
{
  const int b = blockIdx.x >> 6;
  const int l0 = (blockIdx.x & 63) * 64;
  __shared__ float T[64][132];
  const int tid = threadIdx.x;
  #pragma unroll
  for (int j=0;j<8;++j) {
    int f = tid + j*256;
    int l = f >> 5, c4 = f & 31;
    *(float4*)&T[l][c4*4] = *(const float4*)(ysum + (size_t)(b*Ln + l0 + l)*128 + c4*4);
  }
  __syncthreads();
  #pragma unroll
  for (int j=0;j<8;++j) {
    int f = tid + j*256;
    int c = f >> 4, lv = f & 15;
    int bg = b*4 + (c>>5);
    float mean = mr[bg*2];
    float rstd = mr[bg*2+1];
    float gam = gamma[c], bet = beta[c];
    size_t base = (size_t)(b*Cn + c)*Ln + l0 + lv*4;
    float4 xv = *(const float4*)(x + base);
    float4 r;
    r.x = siluf(fmaf((T[lv*4+0][c]-mean)*rstd, gam, bet)) + xv.x;
    r.y = siluf(fmaf((T[lv*4+1][c]-mean)*rstd, gam, bet)) + xv.y;
    r.z = siluf(fmaf((T[lv*4+2][c]-mean)*rstd, gam, bet)) + xv.z;
    r.w = siluf(fmaf((T[lv*4+3][c]-mean)*rstd, gam, bet)) + xv.w;
    *(float4*)(out + base) = r;
  }
}

extern "C" void kernel_launch(void* const* d_in, const int* in_sizes, int n_in,
                              void* d_out, int out_size, void* d_ws, size_t ws_size,
                              hipStream_t stream) {
  const float* x      = (const float*)d_in[0];
  const float* W_in_f = (const float*)d_in[1];
  const float* cw_f   = (const float*)d_in[2];
  const float* cb_f   = (const float*)d_in[3];
  const float* Wx_f   = (const float*)d_in[4];
  const float* Wdt_f  = (const float*)d_in[5];
  const float* bdt_f  = (const float*)d_in[6];
  const float* Al_f   = (const float*)d_in[7];
  const float* D_f    = (const float*)d_in[8];
  const float* Wo_f   = (const float*)d_in[9];
  const float* W_in_b = (const float*)d_in[10];
  const float* cw_b   = (const float*)d_in[11];
  const float* cb_b   = (const float*)d_in[12];
  const float* Wx_b   = (const float*)d_in[13];
  const float* Wdt_b  = (const float*)d_in[14];
  const float* bdt_b  = (const float*)d_in[15];
  const float* Al_b   = (const float*)d_in[16];
  const float* D_b    = (const float*)d_in[17];
  const float* Wo_b   = (const float*)d_in[18];
  const float* gamma  = (const float*)d_in[19];
  const float* beta   = (const float*)d_in[20];
  float* out = (float*)d_out;

  float* w = (float*)d_ws;
  size_t o = 0;
  float* xpr0 = w + o; o += (size_t)ROWS*256;  // xp bf16 region; yp aliases after conv
  float* xpr1 = w + o; o += (size_t)ROWS*256;
  unsigned short* xc0 = (unsigned short*)(w + o); o += (size_t)ROWS*128;
  unsigned short* xc1 = (unsigned short*)(w + o); o += (size_t)ROWS*128;
  unsigned short* zb0 = (unsigned short*)(w + o); o += (size_t)ROWS*128;
  unsigned short* zb1 = (unsigned short*)(w + o); o += (size_t)ROWS*128;
  unsigned short* yg0 = (unsigned short*)(w + o); o += (size_t)ROWS*128;
  unsigned short* yg1 = (unsigned short*)(w + o); o += (size_t)ROWS*128;
  float* xdb0 = w + o; o += (size_t)ROWS*40;   // dead after pass3 -> ysum alias
  float* xdb1 = w + o; o += (size_t)ROWS*40;
  float* sdt0 = w + o; o += (size_t)Bn*NCn*256;
  float* sdt1 = w + o; o += (size_t)Bn*NCn*256;
  unsigned short* hk0 = (unsigned short*)(w + o); o += (size_t)Bn*NCn*16*128;  // bf16
  unsigned short* hk1 = (unsigned short*)(w + o); o += (size_t)Bn*NCn*16*128;
  float* part = w + o; o += 2048;
  float* mr   = w + o; o += 32;
  unsigned short* xp0 = (unsigned short*)xpr0;
  unsigned short* xp1 = (unsigned short*)xpr1;
  float* yp   = xpr0;   // 2 x ROWS*128 f32 = xpr0 (xp dead after conv)
  float* ysum = xdb0;
  if (ws_size < o*sizeof(float)) return;

  k_g1<<<dim3(ROWS/128, 4, 2), 256, 0, stream>>>(x, W_in_f, W_in_b, xp0, xp1, zb0, zb1);
  k_conv<<<dim3(1024, 2), 256, 0, stream>>>(xp0, xp1, cw_f, cw_b, cb_f, cb_b, xc0, xc1);
  k_g2<<<dim3(ROWS/64, 1, 2), 256, 0, stream>>>(xc0, xc1, Wx_f, Wx_b, xdb0, xdb1);
  k_pass1<<<dim3(Bn*NCn*2, 2), 128, 0, stream>>>(xdb0, xdb1, xc0, xc1, Wdt_f, Wdt_b,
                                                 bdt_f, bdt_b, Al_f, Al_b, sdt0, sdt1, hk0, hk1);
  k_pass2<<<dim3(64, 2), 256, 0, stream>>>(Al_f, Al_b, sdt0, sdt1, hk0, hk1);
  k_pass3<<<dim3(Bn*NCn*2, 2), 128, 0, stream>>>(xdb0, xdb1, xc0, xc1, Wdt_f, Wdt_b,
                                                 bdt_f, bdt_b, Al_f, Al_b, D_f, D_b,
                                                 hk0, hk1, zb0, zb1, yg0, yg1);
  k_gout<<<dim3(ROWS/64, 2), 256, 0, stream>>>(yg0, yg1, Wo_f, Wo_b, yp);
  k_gnstat<<<dim3(256), 256, 0, stream>>>(yp, ysum, part);
  k_gnred<<<dim3(1), 64, 0, stream>>>(part, mr);
  k_gnapply<<<dim3(256), 256, 0, stream>>>(ysum, mr, gamma, beta, x, out);
}